// Round 3
// baseline (306.368 us; speedup 1.0000x reference)
//
#include <hip/hip_runtime.h>
#include <hip/hip_bf16.h>
#include <math.h>

// Problem constants
#define NPIX 262144      // 512*512
#define T_B 4
#define T_C 20
#define T_K 16           // KNOWN

// Workspace layout (floats), total 1108 floats = 4432 bytes
//   GP[b][15][16] : packed gram 4x4 blocks, upper-tri of 5x5 block grid
//   SXY[b][16], SY[b][16], BCE[16], SX[4]
#define OFF_GP  0
#define OFF_SXY 960
#define OFF_SY  1024
#define OFF_BCE 1088
#define OFF_SX  1104
#define WS_FLOATS 1108

__device__ __forceinline__ float wave_red(float v) {
#pragma unroll
  for (int off = 32; off > 0; off >>= 1) v += __shfl_xor(v, off, 64);
  return v;
}

// packed index of 4x4 block (I,J), I<=J, in upper-tri of 5x5 block grid
__device__ __forceinline__ int pb_idx(int I, int J) { return I * (11 - I) / 2 + (J - I); }

// ---------------- per-(b,c) linear stats ----------------
__global__ __launch_bounds__(256) void stats_kernel(const float* __restrict__ X,
                                                    const int* __restrict__ Y,
                                                    float* __restrict__ ws) {
  const int c = blockIdx.y;
  const int b = blockIdx.z;
  const size_t base = ((size_t)b * T_C + c) * (size_t)NPIX;
  const float4* X4 = reinterpret_cast<const float4*>(X + base);
  const int n4 = NPIX / 4;
  const int tid = threadIdx.x;
  const int stride = gridDim.x * blockDim.x;

  float s0 = 0.f, s1 = 0.f, s2 = 0.f;  // c<16: sum x*y, sum y, sum log-select ; c>=16: s0 = sum x
  if (c < T_K) {
    const int4* Y4 = reinterpret_cast<const int4*>(Y + base);
    for (int i = blockIdx.x * blockDim.x + tid; i < n4; i += stride) {
      float4 x = X4[i];
      int4 y = Y4[i];
      float xv[4] = {x.x, x.y, x.z, x.w};
      int yv[4] = {y.x, y.y, y.z, y.w};
#pragma unroll
      for (int t = 0; t < 4; t++) {
        float fy = (float)yv[t];
        s0 = fmaf(fy, xv[t], s0);
        s1 += fy;
        // y*log(x) + (1-y)*log1p(-x) with y in {0,1} == log(y ? x : 1-x)
        s2 += __logf(yv[t] ? xv[t] : 1.f - xv[t]);
      }
    }
  } else {
    for (int i = blockIdx.x * blockDim.x + tid; i < n4; i += stride) {
      float4 x = X4[i];
      s0 += (x.x + x.y) + (x.z + x.w);
    }
  }

  s0 = wave_red(s0);
  s1 = wave_red(s1);
  s2 = wave_red(s2);
  __shared__ float red[3][4];
  const int wv = tid >> 6, ln = tid & 63;
  if (ln == 0) { red[0][wv] = s0; red[1][wv] = s1; red[2][wv] = s2; }
  __syncthreads();
  if (tid == 0) {
    float t0 = (red[0][0] + red[0][1]) + (red[0][2] + red[0][3]);
    float t1 = (red[1][0] + red[1][1]) + (red[1][2] + red[1][3]);
    float t2 = (red[2][0] + red[2][1]) + (red[2][2] + red[2][3]);
    if (c < T_K) {
      atomicAdd(&ws[OFF_SXY + b * 16 + c], t0);
      atomicAdd(&ws[OFF_SY + b * 16 + c], t1);
      atomicAdd(&ws[OFF_BCE + c], t2);
    } else {
      atomicAdd(&ws[OFF_SX + (c - T_K)], t0);
    }
  }
}

// ---------------- per-b gram matrix X.X^T (20x20) ----------------
// 15 waves per block; wave w owns 4x4 channel-pair block (I,J), I<=J.
// K-tile of 256 staged in LDS; each lane handles 4 contiguous k (b128 reads).
__global__ __launch_bounds__(960) void gram_kernel(const float* __restrict__ X,
                                                   float* __restrict__ ws) {
  __shared__ float xs[T_C][256];  // 20 KB
  const int tid = threadIdx.x;
  const int wv = tid >> 6;  // 0..14
  const int ln = tid & 63;
  const int b = blockIdx.y;
  const float* Xb = X + (size_t)b * T_C * NPIX;

  int I = 0, w = wv;
  while (w >= 5 - I) { w -= 5 - I; ++I; }
  const int J = I + w;
  const int rowA = 4 * I, rowB = 4 * J;

  float acc[16];
#pragma unroll
  for (int m = 0; m < 16; m++) acc[m] = 0.f;

  const int ntiles = NPIX / 256;  // 1024
  for (int tile = blockIdx.x; tile < ntiles; tile += gridDim.x) {
    const int k0 = tile * 256;
    // stage 20x256 floats, coalesced float4
    for (int idx = tid; idx < T_C * 64; idx += blockDim.x) {
      const int c = idx >> 6;
      const int q = idx & 63;
      const float4 v =
          *reinterpret_cast<const float4*>(Xb + (size_t)c * NPIX + k0 + q * 4);
      *reinterpret_cast<float4*>(&xs[c][q * 4]) = v;
    }
    __syncthreads();
    const int k = ln * 4;
    float4 av[4], bv[4];
#pragma unroll
    for (int r = 0; r < 4; r++) av[r] = *reinterpret_cast<const float4*>(&xs[rowA + r][k]);
#pragma unroll
    for (int r = 0; r < 4; r++) bv[r] = *reinterpret_cast<const float4*>(&xs[rowB + r][k]);
#pragma unroll
    for (int r = 0; r < 4; r++) {
#pragma unroll
      for (int q = 0; q < 4; q++) {
        acc[r * 4 + q] += (av[r].x * bv[q].x + av[r].y * bv[q].y) +
                          (av[r].z * bv[q].z + av[r].w * bv[q].w);
      }
    }
    __syncthreads();
  }

#pragma unroll
  for (int m = 0; m < 16; m++) {
    float v = wave_red(acc[m]);
    if (ln == 0) atomicAdd(&ws[OFF_GP + (b * 15 + wv) * 16 + m], v);
  }
}

// ---------------- finalize: 4 scalars ----------------
__global__ __launch_bounds__(64) void finalize_kernel(const float* __restrict__ ws,
                                                      float* __restrict__ out) {
  const int ln = threadIdx.x;
  const float invBN = 1.f / (4.f * 262144.f);

  // loss3: M = mean_b (G+1)/(s_i+s_j+1); (sum - trace)/(C*(C-1))
  float l3p = 0.f;
  for (int ij = ln; ij < 400; ij += 64) {
    const int i = ij / 20, j = ij % 20;
    if (i == j) continue;
    const int Ii = i >> 2, ri = i & 3, Jj = j >> 2, rj = j & 3;
    float sum = 0.f;
#pragma unroll
    for (int b = 0; b < 4; b++) {
      float g = (Ii <= Jj)
                    ? ws[OFF_GP + (b * 15 + pb_idx(Ii, Jj)) * 16 + ri * 4 + rj]
                    : ws[OFF_GP + (b * 15 + pb_idx(Jj, Ii)) * 16 + rj * 4 + ri];
      float si = ws[OFF_GP + (b * 15 + pb_idx(Ii, Ii)) * 16 + ri * 5];
      float sj = ws[OFF_GP + (b * 15 + pb_idx(Jj, Jj)) * 16 + rj * 5];
      sum += (g + 1.f) / (si + sj + 1.f);
    }
    l3p += sum * 0.25f;
  }
  const float l3 = wave_red(l3p) / 380.f;  // C*(C-1)

  // loss1: dice + bce over first 16 channels
  float l1p = 0.f;
  if (ln < 16) {
    const int c = ln;
    const int Ic = c >> 2, rc = c & 3;
    float d = 0.f;
#pragma unroll
    for (int b = 0; b < 4; b++) {
      float num = ws[OFF_SXY + b * 16 + c] + 1.f;
      float s = ws[OFF_GP + (b * 15 + pb_idx(Ic, Ic)) * 16 + rc * 5];  // sum x^2
      float den = s + ws[OFF_SY + b * 16 + c] + 1.f;                   // sum y^2 == sum y
      d += 1.f - num / den;
    }
    d *= 0.25f;
    float bce = -ws[OFF_BCE + c] * invBN;
    l1p = d + bce;
  }
  const float l1 = wave_red(l1p) * (1.f / 16.f);

  // loss2: -log(clip(mean*50,0,1)) over last 4 channels
  float l2p = 0.f;
  if (ln < 4) {
    float m = ws[OFF_SX + ln] * invBN;
    float v = fminf(fmaxf(m * 50.f, 0.f), 1.f);
    l2p = -logf(v);
  }
  const float l2 = wave_red(l2p) * 0.25f;

  if (ln == 0) {
    out[1] = l1;
    out[2] = l2;
    out[3] = l3;
    out[0] = 0.1f * (l1 + l2 + l3);
  }
}

extern "C" void kernel_launch(void* const* d_in, const int* in_sizes, int n_in,
                              void* d_out, int out_size, void* d_ws, size_t ws_size,
                              hipStream_t stream) {
  const float* X = (const float*)d_in[0];
  const int* Y = (const int*)d_in[1];
  // d_in[2] (class_lst) is unused by the reference.
  float* ws = (float*)d_ws;
  float* out = (float*)d_out;

  hipMemsetAsync(ws, 0, WS_FLOATS * sizeof(float), stream);
  stats_kernel<<<dim3(32, 20, 4), 256, 0, stream>>>(X, Y, ws);
  gram_kernel<<<dim3(128, 4), 960, 0, stream>>>(X, ws);
  finalize_kernel<<<1, 64, 0, stream>>>(ws, out);
}

// Round 6
// 196.291 us; speedup vs baseline: 1.5608x; 1.5608x over previous
//
#include <hip/hip_runtime.h>
#include <math.h>

#define NPIX 262144      // 512*512
#define T_B 4
#define T_C 20
#define T_K 16
#define TILE 256         // k-depth per LDS tile
#define XB 64            // x-blocks per batch; tiles/block = NPIX/TILE/XB = 16
#define NTILES (NPIX / TILE / XB)
#define NCOPY 8          // atomic contention spreading
#define GRAM_F 960       // 4b * 15 pair-blocks * 16
#define PART_F 1200      // + 4b * 20c * 3 slots

__device__ __forceinline__ float wave_red(float v) {
#pragma unroll
  for (int off = 32; off > 0; off >>= 1) v += __shfl_xor(v, off, 64);
  return v;
}
// packed index of 4x4 channel block (I,J), I<=J, upper-tri of 5x5 grid; pb_idx(I,J)==wv
__device__ __forceinline__ int pb_idx(int I, int J) { return I * (11 - I) / 2 + (J - I); }

// One pass over X (+Y for c<16): gram 20x20 per batch AND all linear stats.
// Block = (xb, b): 15 waves; wave wv owns 4x4 pair-block AND stages channel wv
// (+ channel 15+wv for wv<5). Reg-staged LDS (T14: prefetch next tile before
// barriers). Partials to 8-way-spread scratch, no contended atomics.
__global__ __launch_bounds__(960) void fused_kernel(const float* __restrict__ X,
                                                    const int* __restrict__ Y,
                                                    float* __restrict__ pw) {
  __shared__ float xs[T_C][TILE];  // 20 KB
  const int tid = threadIdx.x, wv = tid >> 6, ln = tid & 63;
  const int b = blockIdx.y, xb = blockIdx.x;
  const int copy = xb & (NCOPY - 1);
  const float* Xb = X + (size_t)b * T_C * NPIX;
  const int*   Yb = Y + (size_t)b * T_C * NPIX;

  int I = 0, w = wv;
  while (w >= 5 - I) { w -= 5 - I; ++I; }
  const int J = I + w, rowA = 4 * I, rowB = 4 * J;

  const int c0 = wv;              // 0..14 (always <16: Y needed)
  const bool has2 = (wv < 5);
  const int c1 = 15 + wv;         // 15..19
  const bool y1 = (wv == 0);      // c1==15 still needs Y

  const float* x0p = Xb + (size_t)c0 * NPIX + ln * 4;
  const int*   y0p = Yb + (size_t)c0 * NPIX + ln * 4;
  const float* x1p = Xb + (size_t)c1 * NPIX + ln * 4;
  const int*   y1p = Yb + (size_t)c1 * NPIX + ln * 4;

  float acc[16];
#pragma unroll
  for (int m = 0; m < 16; ++m) acc[m] = 0.f;
  float sxy0 = 0.f, sy0 = 0.f, sb0 = 0.f;
  float sxy1 = 0.f, sy1 = 0.f, sb1 = 0.f, sx1 = 0.f;

  // prologue loads (tile 0 of this block)
  int k0 = xb * TILE;
  float4 xr0 = *(const float4*)(x0p + k0);
  int4   yr0 = *(const int4*)(y0p + k0);
  float4 xr1; int4 yr1;
  if (has2) xr1 = *(const float4*)(x1p + k0);
  if (y1)   yr1 = *(const int4*)(y1p + k0);

  for (int t = 0; t < NTILES; ++t) {
    // write staged regs to LDS (compiler inserts the vmcnt wait here — "write-late")
    *(float4*)&xs[c0][ln * 4] = xr0;
    if (has2) *(float4*)&xs[c1][ln * 4] = xr1;

    // stats from the staged registers (free ride on the staging pass)
    {
      float xv[4] = {xr0.x, xr0.y, xr0.z, xr0.w};
      int   yv[4] = {yr0.x, yr0.y, yr0.z, yr0.w};
#pragma unroll
      for (int u = 0; u < 4; ++u) {
        float fy = (float)yv[u];
        sxy0 = fmaf(fy, xv[u], sxy0);
        sy0 += fy;
        // y*log(x) + (1-y)*log1p(-x), y in {0,1}  ==  log(y ? x : 1-x)
        sb0 += __logf(yv[u] ? xv[u] : 1.f - xv[u]);
      }
    }
    if (has2) {
      float xv[4] = {xr1.x, xr1.y, xr1.z, xr1.w};
      if (y1) {
        int yv[4] = {yr1.x, yr1.y, yr1.z, yr1.w};
#pragma unroll
        for (int u = 0; u < 4; ++u) {
          float fy = (float)yv[u];
          sxy1 = fmaf(fy, xv[u], sxy1);
          sy1 += fy;
          sb1 += __logf(yv[u] ? xv[u] : 1.f - xv[u]);
        }
      } else {
        sx1 += (xv[0] + xv[1]) + (xv[2] + xv[3]);
      }
    }

    // issue next tile's global loads EARLY (hide HBM latency under compute)
    if (t + 1 < NTILES) {
      int k0n = (xb + (t + 1) * XB) * TILE;
      xr0 = *(const float4*)(x0p + k0n);
      yr0 = *(const int4*)(y0p + k0n);
      if (has2) xr1 = *(const float4*)(x1p + k0n);
      if (y1)   yr1 = *(const int4*)(y1p + k0n);
    }
    __syncthreads();

    // gram compute on current LDS tile
    const int k = ln * 4;
    float4 av[4], bv[4];
#pragma unroll
    for (int r = 0; r < 4; ++r) av[r] = *(const float4*)&xs[rowA + r][k];
#pragma unroll
    for (int r = 0; r < 4; ++r) bv[r] = *(const float4*)&xs[rowB + r][k];
#pragma unroll
    for (int r = 0; r < 4; ++r)
#pragma unroll
      for (int q = 0; q < 4; ++q)
        acc[r * 4 + q] += (av[r].x * bv[q].x + av[r].y * bv[q].y) +
                          (av[r].z * bv[q].z + av[r].w * bv[q].w);
    __syncthreads();
  }

  // partial outputs: 8-way copy spreading => only 8 writers per address
  float* pc = pw + copy * PART_F;
#pragma unroll
  for (int m = 0; m < 16; ++m) {
    float v = wave_red(acc[m]);
    if (ln == 0) atomicAdd(&pc[(b * 15 + wv) * 16 + m], v);
  }
  float v;
  v = wave_red(sxy0); if (ln == 0) atomicAdd(&pc[GRAM_F + (b * T_C + c0) * 3 + 0], v);
  v = wave_red(sy0);  if (ln == 0) atomicAdd(&pc[GRAM_F + (b * T_C + c0) * 3 + 1], v);
  v = wave_red(sb0);  if (ln == 0) atomicAdd(&pc[GRAM_F + (b * T_C + c0) * 3 + 2], v);
  if (has2) {
    if (y1) {
      v = wave_red(sxy1); if (ln == 0) atomicAdd(&pc[GRAM_F + (b * T_C + c1) * 3 + 0], v);
      v = wave_red(sy1);  if (ln == 0) atomicAdd(&pc[GRAM_F + (b * T_C + c1) * 3 + 1], v);
      v = wave_red(sb1);  if (ln == 0) atomicAdd(&pc[GRAM_F + (b * T_C + c1) * 3 + 2], v);
    } else {
      v = wave_red(sx1);  if (ln == 0) atomicAdd(&pc[GRAM_F + (b * T_C + c1) * 3 + 0], v);
    }
  }
}

// ---------------- finalize: sum 8 copies, compute 4 scalars ----------------
__global__ __launch_bounds__(64) void finalize_kernel(const float* __restrict__ pw,
                                                      float* __restrict__ out) {
  __shared__ float red[PART_F];
  const int ln = threadIdx.x;
  for (int o = ln; o < PART_F; o += 64) {
    float s = 0.f;
#pragma unroll
    for (int c8 = 0; c8 < NCOPY; ++c8) s += pw[c8 * PART_F + o];
    red[o] = s;
  }
  __syncthreads();
  const float invBN = 1.f / (4.f * 262144.f);

  // loss3
  float l3p = 0.f;
  for (int ij = ln; ij < 400; ij += 64) {
    const int i = ij / 20, j = ij % 20;
    if (i == j) continue;
    const int Ii = i >> 2, ri = i & 3, Jj = j >> 2, rj = j & 3;
    float sum = 0.f;
#pragma unroll
    for (int b = 0; b < 4; ++b) {
      float g = (Ii <= Jj) ? red[(b * 15 + pb_idx(Ii, Jj)) * 16 + ri * 4 + rj]
                           : red[(b * 15 + pb_idx(Jj, Ii)) * 16 + rj * 4 + ri];
      float si = red[(b * 15 + pb_idx(Ii, Ii)) * 16 + ri * 5];
      float sj = red[(b * 15 + pb_idx(Jj, Jj)) * 16 + rj * 5];
      sum += (g + 1.f) / (si + sj + 1.f);
    }
    l3p += sum * 0.25f;
  }
  const float l3 = wave_red(l3p) / 380.f;

  // loss1: dice + bce, c<16
  float l1p = 0.f;
  if (ln < 16) {
    const int c = ln, Ic = c >> 2, rc = c & 3;
    float d = 0.f, bsum = 0.f;
#pragma unroll
    for (int b = 0; b < 4; ++b) {
      float num = red[GRAM_F + (b * T_C + c) * 3 + 0] + 1.f;
      float s = red[(b * 15 + pb_idx(Ic, Ic)) * 16 + rc * 5];      // sum x^2 (gram diag)
      float den = s + red[GRAM_F + (b * T_C + c) * 3 + 1] + 1.f;   // + sum y
      d += 1.f - num / den;
      bsum += red[GRAM_F + (b * T_C + c) * 3 + 2];
    }
    l1p = d * 0.25f - bsum * invBN;
  }
  const float l1 = wave_red(l1p) * (1.f / 16.f);

  // loss2: c>=16
  float l2p = 0.f;
  if (ln >= 16 && ln < 20) {
    float s = 0.f;
#pragma unroll
    for (int b = 0; b < 4; ++b) s += red[GRAM_F + (b * T_C + ln) * 3 + 0];
    float m = s * invBN;
    float vv = fminf(fmaxf(m * 50.f, 0.f), 1.f);
    l2p = -logf(vv);
  }
  const float l2 = wave_red(l2p) * 0.25f;

  if (ln == 0) {
    out[1] = l1; out[2] = l2; out[3] = l3;
    out[0] = 0.1f * (l1 + l2 + l3);
  }
}

extern "C" void kernel_launch(void* const* d_in, const int* in_sizes, int n_in,
                              void* d_out, int out_size, void* d_ws, size_t ws_size,
                              hipStream_t stream) {
  const float* X = (const float*)d_in[0];
  const int* Y = (const int*)d_in[1];
  float* ws = (float*)d_ws;
  float* out = (float*)d_out;

  hipMemsetAsync(ws, 0, NCOPY * PART_F * sizeof(float), stream);
  fused_kernel<<<dim3(XB, T_B), 960, 0, stream>>>(X, Y, ws);
  finalize_kernel<<<1, 64, 0, stream>>>(ws, out);
}